// Round 4
// baseline (585.062 us; speedup 1.0000x reference)
//
#include <hip/hip_runtime.h>
#include <hip/hip_bf16.h>
#include <cstdint>
#include <cstddef>

#define B_   32
#define S_   2048
#define DH_  1024
#define DF_  1024
#define DM_  512
#define MTOT (B_ * S_)   // 65536
#define NK   (DF_ / 32)  // 32 K-iterations

typedef __attribute__((ext_vector_type(8))) short bf16x8;
typedef __attribute__((ext_vector_type(4))) float f32x4;

#define AS1 __attribute__((address_space(1)))
#define AS3 __attribute__((address_space(3)))

static __device__ __forceinline__ void load_lds16(const void* g, void* l) {
    __builtin_amdgcn_global_load_lds((const AS1 unsigned*)g, (AS3 unsigned*)l,
                                     16, 0, 0);
}

// fp32 pair -> packed bf16, round-half-up (cheap)
static __device__ __forceinline__ unsigned pack_rhu(float a, float b) {
    unsigned ua = (__float_as_uint(a) + 0x8000u) >> 16;
    unsigned ub = (__float_as_uint(b) + 0x8000u) & 0xFFFF0000u;
    return ua | ub;
}

static __device__ __forceinline__ float tanh_fast(float x) {
    float e = __expf(2.0f * x);
    return 1.0f - 2.0f / (e + 1.0f);
}

// ---------------------------------------------------------------------------
// embh[b][m] = dot(hidden[b], W1h[m]) + b1h[m] + b1f[m]
// ---------------------------------------------------------------------------
__global__ __launch_bounds__(256) void k_embh(
    const float* __restrict__ hidden, const float* __restrict__ W1h,
    const float* __restrict__ b1h, const float* __restrict__ b1f,
    float* __restrict__ embh)
{
    int b  = blockIdx.x;
    int mg = blockIdx.y;
    int t  = threadIdx.x;
    int m  = mg * 64 + (t >> 2);
    int kp = (t & 3) * 256;
    const float4* h4 = (const float4*)(hidden + (size_t)b * DH_ + kp);
    const float4* w4 = (const float4*)(W1h + (size_t)m * DH_ + kp);
    float s = 0.0f;
    #pragma unroll 8
    for (int i = 0; i < 64; ++i) {
        float4 a = h4[i];
        float4 w = w4[i];
        s += a.x * w.x + a.y * w.y + a.z * w.z + a.w * w.w;
    }
    s += __shfl_xor(s, 1);
    s += __shfl_xor(s, 2);
    if ((t & 3) == 0)
        embh[b * DM_ + m] = s + b1h[m] + b1f[m];
}

// ---------------------------------------------------------------------------
// fp32 -> bf16 streaming convert; 8 elements per thread
// ---------------------------------------------------------------------------
__global__ __launch_bounds__(256) void k_cvt(
    const float* __restrict__ src, unsigned short* __restrict__ dst)
{
    size_t i = (size_t)blockIdx.x * 256 + threadIdx.x;
    float4 a = ((const float4*)src)[2 * i];
    float4 b = ((const float4*)src)[2 * i + 1];
    uint4 r;
    r.x = pack_rhu(a.x, a.y);
    r.y = pack_rhu(a.z, a.w);
    r.z = pack_rhu(b.x, b.y);
    r.w = pack_rhu(b.z, b.w);
    ((uint4*)dst)[i] = r;
}

// ---------------------------------------------------------------------------
// MAIN GEMM: 128x128 tile, BK=32, mfma_f32_16x16x32_bf16, 4 waves (2x2).
//   ONE barrier per iteration, double-buffered LDS (2 x 16 KB), ALL staging
//   via async global_load_lds width=16 issued right after the barrier ->
//   each load has a full iteration slot of latency budget.
//   Grid swizzle: 4 bx-sharers of an A-tile == mod 8 -> same XCD L2.
// ---------------------------------------------------------------------------
__global__ __launch_bounds__(256) void k_gemm_bf(
    const unsigned short* __restrict__ fb, const unsigned short* __restrict__ wb,
    const float* __restrict__ embh, const float* __restrict__ w2,
    float* __restrict__ plog)
{
    __shared__ bf16x8 As[2][4 * 128];   // 2 x 8 KB
    __shared__ bf16x8 Bs[2][4 * 128];   // 2 x 8 KB

    const int t    = threadIdx.x;
    const int lane = t & 63;
    const int w    = t >> 6;
    const int wm   = w >> 1;
    const int wn   = w & 1;
    const int quad = lane >> 4;
    const int l16  = lane & 15;

    const int blk   = blockIdx.x;
    const int panel = blk >> 5;
    const int sub   = blk & 31;
    const int bx    = sub >> 3;                // 0..3   N tile
    const int by    = panel * 8 + (sub & 7);   // 0..511 M tile

    // staging: wave w covers k-chunk c=w (8 bf16); 2 instrs = rows 0..63/64..127
    const unsigned short* aG0 = fb + ((size_t)(by * 128) + lane) * DF_ + w * 8;
    const unsigned short* aG1 = aG0 + (size_t)64 * DF_;
    const unsigned short* bG0 = wb + ((size_t)(bx * 128) + lane) * DF_ + w * 8;
    const unsigned short* bG1 = bG0 + (size_t)64 * DF_;

    f32x4 acc[4][4];
    const f32x4 zero = {0.0f, 0.0f, 0.0f, 0.0f};
    #pragma unroll
    for (int i = 0; i < 4; ++i)
        #pragma unroll
        for (int j = 0; j < 4; ++j) acc[i][j] = zero;

    // prologue: loads for kt=0 -> buf0
    load_lds16(aG0, &As[0][w * 128]);
    load_lds16(aG1, &As[0][w * 128 + 64]);
    load_lds16(bG0, &Bs[0][w * 128]);
    load_lds16(bG1, &Bs[0][w * 128 + 64]);

    #pragma unroll 2
    for (int kt = 0; kt < NK; ++kt) {
        const int cur = kt & 1;
        const int nxt = cur ^ 1;

        __syncthreads();   // drains vmcnt -> buf[cur] ready; buf[nxt] readers done

        if (kt + 1 < NK) {   // issue kt+1 -> buf[nxt]; full iteration to land
            load_lds16(aG0 + (kt + 1) * 32, &As[nxt][w * 128]);
            load_lds16(aG1 + (kt + 1) * 32, &As[nxt][w * 128 + 64]);
            load_lds16(bG0 + (kt + 1) * 32, &Bs[nxt][w * 128]);
            load_lds16(bG1 + (kt + 1) * 32, &Bs[nxt][w * 128 + 64]);
        }

        bf16x8 af[4], bfr[4];
        #pragma unroll
        for (int mi = 0; mi < 4; ++mi)
            af[mi] = As[cur][quad * 128 + wm * 64 + mi * 16 + l16];
        #pragma unroll
        for (int nj = 0; nj < 4; ++nj)
            bfr[nj] = Bs[cur][quad * 128 + wn * 64 + nj * 16 + l16];

        #pragma unroll
        for (int mi = 0; mi < 4; ++mi)
            #pragma unroll
            for (int nj = 0; nj < 4; ++nj)
                acc[mi][nj] = __builtin_amdgcn_mfma_f32_16x16x32_bf16(
                    af[mi], bfr[nj], acc[mi][nj], 0, 0, 0);
    }

    // epilogue: C/D 16x16 layout col=l16, row=quad*4+reg (validated R1-R3)
    const int bIdx = by >> 4;
    float ew[4], wv[4];
    #pragma unroll
    for (int nj = 0; nj < 4; ++nj) {
        int c = bx * 128 + wn * 64 + nj * 16 + l16;
        ew[nj] = embh[bIdx * DM_ + c];
        wv[nj] = w2[c];
    }
    float* plw = plog + (size_t)(bx * 2 + wn) * MTOT + bIdx * S_;
    #pragma unroll
    for (int mi = 0; mi < 4; ++mi) {
        #pragma unroll
        for (int reg = 0; reg < 4; ++reg) {
            float p = 0.0f;
            #pragma unroll
            for (int nj = 0; nj < 4; ++nj)
                p += tanh_fast(acc[mi][nj][reg] + ew[nj]) * wv[nj];
            p += __shfl_xor(p, 1);
            p += __shfl_xor(p, 2);
            p += __shfl_xor(p, 4);
            p += __shfl_xor(p, 8);
            if (l16 == 0) {
                int rowl = wm * 64 + mi * 16 + quad * 4 + reg;
                int s = (by * 128 + rowl) & (S_ - 1);
                plw[s] = p;
            }
        }
    }
}

// ---------------------------------------------------------------------------
// FALLBACK GEMM (fp32 A, in-kernel pack) — only if ws too small for bf16 feats
// ---------------------------------------------------------------------------
__global__ __launch_bounds__(256) void k_gemm_f32(
    const float* __restrict__ feats, const unsigned short* __restrict__ w1fb,
    const float* __restrict__ embh, const float* __restrict__ w2,
    float* __restrict__ plog)
{
    __shared__ bf16x8 As[4 * 128];
    __shared__ bf16x8 Bs[4 * 128];

    const int t    = threadIdx.x;
    const int lane = t & 63;
    const int w    = t >> 6;
    const int wm   = w >> 1;
    const int wn   = w & 1;
    const int quad = lane >> 4;
    const int l16  = lane & 15;
    const int blk   = blockIdx.x;
    const int panel = blk >> 5;
    const int sub   = blk & 31;
    const int bx    = sub >> 3;
    const int by    = panel * 8 + (sub & 7);

    const int sRow = t >> 1;
    const int sK   = (t & 1) * 16;
    const int c0   = sK >> 3;
    const float*          aG = feats + (size_t)(by * 128 + sRow) * DF_ + sK;
    const unsigned short* bG = w1fb  + (size_t)(bx * 128 + sRow) * DF_ + sK;

    f32x4 acc[4][4];
    const f32x4 zero = {0.0f, 0.0f, 0.0f, 0.0f};
    #pragma unroll
    for (int i = 0; i < 4; ++i)
        #pragma unroll
        for (int j = 0; j < 4; ++j) acc[i][j] = zero;

    for (int kt = 0; kt < NK; ++kt) {
        float4 a0 = *(const float4*)(aG + kt * 32);
        float4 a1 = *(const float4*)(aG + kt * 32 + 4);
        float4 a2 = *(const float4*)(aG + kt * 32 + 8);
        float4 a3 = *(const float4*)(aG + kt * 32 + 12);
        uint4  b0 = *(const uint4*)(bG + kt * 32);
        uint4  b1 = *(const uint4*)(bG + kt * 32 + 8);

        __syncthreads();

        union { unsigned u[4]; bf16x8 v; } pa;
        pa.u[0] = pack_rhu(a0.x, a0.y);
        pa.u[1] = pack_rhu(a0.z, a0.w);
        pa.u[2] = pack_rhu(a1.x, a1.y);
        pa.u[3] = pack_rhu(a1.z, a1.w);
        As[c0 * 128 + sRow] = pa.v;
        pa.u[0] = pack_rhu(a2.x, a2.y);
        pa.u[1] = pack_rhu(a2.z, a2.w);
        pa.u[2] = pack_rhu(a3.x, a3.y);
        pa.u[3] = pack_rhu(a3.z, a3.w);
        As[(c0 + 1) * 128 + sRow] = pa.v;

        union { uint4 q; bf16x8 v; } pb;
        pb.q = b0;
        Bs[c0 * 128 + sRow] = pb.v;
        pb.q = b1;
        Bs[(c0 + 1) * 128 + sRow] = pb.v;

        __syncthreads();

        bf16x8 af[4], bfr[4];
        #pragma unroll
        for (int mi = 0; mi < 4; ++mi)
            af[mi] = As[quad * 128 + wm * 64 + mi * 16 + l16];
        #pragma unroll
        for (int nj = 0; nj < 4; ++nj)
            bfr[nj] = Bs[quad * 128 + wn * 64 + nj * 16 + l16];

        #pragma unroll
        for (int mi = 0; mi < 4; ++mi)
            #pragma unroll
            for (int nj = 0; nj < 4; ++nj)
                acc[mi][nj] = __builtin_amdgcn_mfma_f32_16x16x32_bf16(
                    af[mi], bfr[nj], acc[mi][nj], 0, 0, 0);
    }

    const int bIdx = by >> 4;
    float ew[4], wv[4];
    #pragma unroll
    for (int nj = 0; nj < 4; ++nj) {
        int c = bx * 128 + wn * 64 + nj * 16 + l16;
        ew[nj] = embh[bIdx * DM_ + c];
        wv[nj] = w2[c];
    }
    float* plw = plog + (size_t)(bx * 2 + wn) * MTOT + bIdx * S_;
    #pragma unroll
    for (int mi = 0; mi < 4; ++mi) {
        #pragma unroll
        for (int reg = 0; reg < 4; ++reg) {
            float p = 0.0f;
            #pragma unroll
            for (int nj = 0; nj < 4; ++nj)
                p += tanh_fast(acc[mi][nj][reg] + ew[nj]) * wv[nj];
            p += __shfl_xor(p, 1);
            p += __shfl_xor(p, 2);
            p += __shfl_xor(p, 4);
            p += __shfl_xor(p, 8);
            if (l16 == 0) {
                int rowl = wm * 64 + mi * 16 + quad * 4 + reg;
                int s = (by * 128 + rowl) & (S_ - 1);
                plw[s] = p;
            }
        }
    }
}

// ---------------------------------------------------------------------------
// combine 8 partials, softmax over S per batch row
// ---------------------------------------------------------------------------
__global__ __launch_bounds__(256) void k_softmax(
    const float* __restrict__ plog, float* __restrict__ probs_out)
{
    int b = blockIdx.x;
    int t = threadIdx.x;
    float l[8];
    #pragma unroll
    for (int i = 0; i < 8; ++i) {
        int s = t + i * 256;
        float sum = 0.0f;
        #pragma unroll
        for (int p = 0; p < 8; ++p)
            sum += plog[(size_t)p * MTOT + b * S_ + s];
        l[i] = sum;
    }
    float mx = l[0];
    #pragma unroll
    for (int i = 1; i < 8; ++i) mx = fmaxf(mx, l[i]);
    #pragma unroll
    for (int off = 1; off < 64; off <<= 1) mx = fmaxf(mx, __shfl_xor(mx, off));
    __shared__ float redm[4];
    __shared__ float reds[4];
    int wid = t >> 6;
    if ((t & 63) == 0) redm[wid] = mx;
    __syncthreads();
    mx = fmaxf(fmaxf(redm[0], redm[1]), fmaxf(redm[2], redm[3]));

    float e[8];
    float es = 0.0f;
    #pragma unroll
    for (int i = 0; i < 8; ++i) {
        e[i] = __expf(l[i] - mx);
        es += e[i];
    }
    #pragma unroll
    for (int off = 1; off < 64; off <<= 1) es += __shfl_xor(es, off);
    if ((t & 63) == 0) reds[wid] = es;
    __syncthreads();
    es = reds[0] + reds[1] + reds[2] + reds[3];
    float inv = 1.0f / es;
    #pragma unroll
    for (int i = 0; i < 8; ++i)
        probs_out[b * S_ + t + i * 256] = e[i] * inv;
}

// ---------------------------------------------------------------------------
// context partials (bf16 feats), 16 s-chunks of 128
// ---------------------------------------------------------------------------
__global__ __launch_bounds__(256) void k_context_bf(
    const unsigned short* __restrict__ fb, const float* __restrict__ probs,
    float* __restrict__ ctxp)
{
    int dp = blockIdx.x * 256 + threadIdx.x;   // d-pair
    int b  = blockIdx.y;
    int z  = blockIdx.z;
    const unsigned* f  = (const unsigned*)(fb + ((size_t)b * S_ + z * 128) * DF_) + dp;
    const float*    pr = probs + b * S_ + z * 128;
    float a0 = 0.0f, a1 = 0.0f;
    #pragma unroll 4
    for (int i = 0; i < 128; ++i) {
        unsigned v = f[(size_t)i * (DF_ / 2)];
        float lo = __uint_as_float(v << 16);
        float hi = __uint_as_float(v & 0xFFFF0000u);
        float p = pr[i];
        a0 += p * lo;
        a1 += p * hi;
    }
    float2* o = (float2*)(ctxp + ((size_t)z * B_ + b) * DF_) + dp;
    *o = make_float2(a0, a1);
}

// fp32-feats fallback context (8 chunks of 256)
__global__ __launch_bounds__(256) void k_context_f32(
    const float* __restrict__ feats, const float* __restrict__ probs,
    float* __restrict__ ctxp)
{
    int d  = blockIdx.x * 256 + threadIdx.x;
    int b  = blockIdx.y;
    int z  = blockIdx.z;
    const float* f  = feats + ((size_t)b * S_ + z * 256) * DF_ + d;
    const float* pr = probs + b * S_ + z * 256;
    float acc = 0.0f;
    #pragma unroll 4
    for (int i = 0; i < 256; ++i)
        acc += pr[i] * f[(size_t)i * DF_];
    ctxp[((size_t)z * B_ + b) * DF_ + d] = acc;
}

template <int NZ>
__global__ __launch_bounds__(256) void k_ctx_red(
    const float* __restrict__ ctxp, float* __restrict__ ctx)
{
    int i = blockIdx.x * 256 + threadIdx.x;
    float s = 0.0f;
    #pragma unroll
    for (int z = 0; z < NZ; ++z)
        s += ctxp[(size_t)z * B_ * DF_ + i];
    ctx[i] = s;
}

// ---------------------------------------------------------------------------
extern "C" void kernel_launch(void* const* d_in, const int* in_sizes, int n_in,
                              void* d_out, int out_size, void* d_ws, size_t ws_size,
                              hipStream_t stream)
{
    const float* hidden = (const float*)d_in[0];
    const float* feats  = (const float*)d_in[1];
    const float* W1h    = (const float*)d_in[2];
    const float* b1h    = (const float*)d_in[3];
    const float* W1f    = (const float*)d_in[4];
    const float* b1f    = (const float*)d_in[5];
    const float* w2     = (const float*)d_in[6];

    float* out   = (float*)d_out;
    float* ctx   = out;              // [B, DF]   (output 0)
    float* probs = out + B_ * DF_;   // [B, 1, S] (output 1)

    char* ws = (char*)d_ws;
    float*          embh  = (float*)ws;                              // 64 KB
    unsigned short* w1fb  = (unsigned short*)(ws + (64 << 10));      // 1 MB
    float*          plog  = (float*)(ws + (64 << 10) + (1 << 20));   // 2 MB
    float*          ctxp  = (float*)(ws + (64 << 10) + (3 << 20));   // up to 2 MB
    unsigned short* featb = (unsigned short*)(ws + (8 << 20));       // 128 MB

    const bool big_ws = ws_size >= ((size_t)8 << 20) + ((size_t)B_ * S_ * DF_ * 2);

    k_embh<<<dim3(B_, DM_ / 64), 256, 0, stream>>>(hidden, W1h, b1h, b1f, embh);
    k_cvt<<<dim3((DM_ * DF_ / 8) / 256), 256, 0, stream>>>(W1f, w1fb);

    if (big_ws) {
        k_cvt<<<dim3(((size_t)MTOT * DF_ / 8) / 256), 256, 0, stream>>>(feats, featb);
        k_gemm_bf<<<dim3((MTOT / 128) * (DM_ / 128)), 256, 0, stream>>>(
            featb, w1fb, embh, w2, plog);
        k_softmax<<<dim3(B_), 256, 0, stream>>>(plog, probs);
        k_context_bf<<<dim3(DF_ / 512, B_, 16), 256, 0, stream>>>(featb, probs, ctxp);
        k_ctx_red<16><<<dim3(B_ * DF_ / 256), 256, 0, stream>>>(ctxp, ctx);
    } else {
        k_gemm_f32<<<dim3((MTOT / 128) * (DM_ / 128)), 256, 0, stream>>>(
            feats, w1fb, embh, w2, plog);
        k_softmax<<<dim3(B_), 256, 0, stream>>>(plog, probs);
        k_context_f32<<<dim3(DF_ / 256, B_, 8), 256, 0, stream>>>(feats, probs, ctxp);
        k_ctx_red<8><<<dim3(B_ * DF_ / 256), 256, 0, stream>>>(ctxp, ctx);
    }
}